// Round 5
// baseline (1022.205 us; speedup 1.0000x reference)
//
#include <hip/hip_runtime.h>
#include <hip/hip_bf16.h>
#include <stdint.h>

#define D_IN    1408
#define D_HID   256
#define N_HEADS 32
#define BATCH   16384

#define BM 256            // rows per block
#define BN 256            // full head of hidden units
#define BK 64
#define KTILES (D_IN / BK)   // 22, exact (even -> static double-buffer parity)
#define NSEG 8               // segments per persistent block

typedef unsigned short u16;
typedef short short8 __attribute__((ext_vector_type(8)));
typedef float f32x4 __attribute__((ext_vector_type(4)));

// All inputs and the output are float32 (reference dtypes); compute is bf16
// MFMA (absmax 7.8e-3 vs threshold 2.4e-2, verified R1-R4).
__device__ __forceinline__ u16 f2b(float f) {
  __hip_bfloat16 h = __float2bfloat16(f);
  return *(u16*)&h;
}

// async global->LDS DMA, 16B/lane; LDS dest = wave-uniform base + lane*16.
__device__ __forceinline__ void gload_lds16(const void* g, void* l) {
  __builtin_amdgcn_global_load_lds(
      (const __attribute__((address_space(1))) uint32_t*)((const uint32_t*)g),
      (__attribute__((address_space(3))) uint32_t*)((uint32_t*)l),
      16, 0, 0);
}

// ---------------------------------------------------------------------------
// Kernel 0 (fused prep): convert X f32->bf16  AND  transpose W1 -> W1T bf16.
// ---------------------------------------------------------------------------
#define CONV_BLOCKS 22528   // (BATCH*D_IN/4)/256 float4s
__global__ void prep(const float4* __restrict__ X, ushort4* __restrict__ Xb,
                     const float* __restrict__ W1, u16* __restrict__ W1T) {
  const int bid = blockIdx.x;
  const int tid = threadIdx.x;
  if (bid < CONV_BLOCKS) {
    int i = bid * 256 + tid;
    float4 v = X[i];
    ushort4 o;
    o.x = f2b(v.x); o.y = f2b(v.y); o.z = f2b(v.z); o.w = f2b(v.w);
    Xb[i] = o;
    return;
  }
  // transpose part: b = f + 22*(o + 4*h)
  __shared__ u16 tile[64][68];
  const int b  = bid - CONV_BLOCKS;
  const int f0 = (b % 22) * 64;
  const int o0 = ((b / 22) & 3) * 64;
  const int h  = b / 88;
  const int tx = tid & 63;
  const int ty = tid >> 6;          // 0..3
  const size_t ib = (size_t)h * D_IN * D_HID;
  #pragma unroll
  for (int i = ty; i < 64; i += 4)
    tile[i][tx] = f2b(W1[ib + (size_t)(f0 + i) * D_HID + o0 + tx]);
  __syncthreads();
  const size_t ob = (size_t)h * D_HID * D_IN;
  #pragma unroll
  for (int pass = 0; pass < 4; ++pass) {
    int r = pass * 16 + ty * 4 + (tx >> 4);  // 0..63
    int c = (tx & 15) * 4;                   // 0..60
    ushort4 v;
    v.x = tile[c + 0][r]; v.y = tile[c + 1][r];
    v.z = tile[c + 2][r]; v.w = tile[c + 3][r];
    *(ushort4*)&W1T[ob + (size_t)(o0 + r) * D_IN + f0 + c] = v;
  }
}

// ---------------------------------------------------------------------------
// Kernel 1: PERSISTENT 256x256 GEMM, 4 waves of 128x128, 1 wave/SIMD.
//
// R2-R4 post-mortem: LDS-read (~2260cy/tile) and MFMA (~2480cy/tile)
// SERIALIZE in every structure where fragment registers are single-set
// (WAR hazard blocks read-ahead), and frag double-buffering (+64 VGPR) is
// infeasible at the 2-waves/SIMD 256-reg cap with 128x64 wave tiles.
// R4's TLP route failed on drain latency (1-tile lead, ~300cy cover).
// This rev goes to the one point where the register math clears:
//   - wave tile 128x128: acc 8x8 f32x4 = 256 regs + DOUBLE-BUFFERED frag
//     sets (fa0/fb0/fa1/fb1 = 128 regs) + addressing ~ 440 <= 512 regs
//     at 1 wave/SIMD (__launch_bounds__(256,1)). 4 waves/block, 1 block/CU.
//   - LDS traffic per FLOP falls 1.5x ((128+128)/128^2 vs (128+64)/(128*64)):
//     ~110us total LDS vs ~182us MFMA floor -> LDS fully hideable.
//   - per K32-step: issue 32 ds_reads (both k-slices) + 8 stage-DMAs, then
//     64 INDEPENDENT MFMAs (64 distinct accs) = ~1240cy of queued matrix-
//     pipe work. Reads for slice 1 are serviced under slice 0's MFMAs; the
//     pipe drains across the tile-end barrier while next tile's reads load.
//   - vmcnt(0) per tile is now FREE: stage loads issued 1240-2480cy before
//     the drain >> 900cy HBM latency. 2 LDS buffers, ONE barrier per tile.
//   - stage safety: stage(t+1)->buf^1 issued after barrier(t-1), and all
//     reads of buf^1's old data completed before their consuming MFMAs
//     (lgkm) which precede barrier(t-1). Single-barrier proof, no lockstep.
// Persistent head-constant blocks (b1/W2 in LDS), 8 segments, same XOR
// swizzle as R1-R4 (0 bank conflicts measured).
// ---------------------------------------------------------------------------
__global__ __launch_bounds__(256, 1) void mano_gemm(
    const u16* __restrict__ X,               // [16384][1408] bf16 (ws)
    const u16* __restrict__ W1T,             // [32][256][1408] bf16 (ws)
    const float* __restrict__ b1,            // [32][256] f32
    const float* __restrict__ W2,            // [32][256][3] f32
    const float* __restrict__ b2,            // [32][3] f32
    float* __restrict__ out)                 // [16384][96] f32 (d_out)
{
  __shared__ __align__(16) u16 As[2][BM * BK];   // 2 x 32 KB
  __shared__ __align__(16) u16 Bs[2][BN * BK];   // 2 x 32 KB
  __shared__ __align__(16) float scr[1536];      // 6 KB epilogue scratch
  __shared__ float b1L[256];                     // head-constant params
  __shared__ float w2L[768];
  __shared__ float b2L[3];

  const int tid  = threadIdx.x;     // 0..255
  const int lane = tid & 63;
  const int wid  = tid >> 6;        // 0..3
  const int quad = lane >> 4;
  const int l15  = lane & 15;
  const int wm   = wid >> 1;        // 0..1 (128-row half)
  const int wn   = wid & 1;         // 0..1 (128-col half)

  const int bid  = blockIdx.x;              // 0..255
  const int head = (bid & 7) * 4 + ((bid >> 3) & 3);   // constant per block
  const int u2   = bid >> 5;                           // 0..7

  const u16* Bu = W1T + (size_t)head * D_HID * D_IN;

  // ---- head-constant params -> LDS (once) ----
  b1L[tid] = b1[head * D_HID + tid];
  #pragma unroll
  for (int i = tid; i < 768; i += 256) w2L[i] = W2[(size_t)head * D_HID * 3 + i];
  if (tid < 3) b2L[tid] = b2[head * 3 + tid];

  // staging: LDS chunk ci(16B) holds global [row=ci>>3][k8=(ci&7)^(row&7)]
  // (XOR pre-swizzled source, linear LDS). 2048 chunks per 256x64 tile,
  // 256 threads -> 8 rounds; same offsets serve A and B.
  int soff[8];
  #pragma unroll
  for (int c = 0; c < 8; ++c) {
    int ci  = c * 256 + tid;
    int row = ci >> 3;                 // 0..255
    int k8  = (ci & 7) ^ (row & 7);
    soff[c] = row * D_IN + k8 * 8;
  }

#define STG_A(BI, P) do { _Pragma("unroll")                                    \
    for (int c = 0; c < 8; ++c)                                                \
      gload_lds16((P) + soff[c], &As[BI][(c * 256 + wid * 64) * 8]); } while (0)
#define STG_B(BI, P) do { _Pragma("unroll")                                    \
    for (int c = 0; c < 8; ++c)                                                \
      gload_lds16((P) + soff[c], &Bs[BI][(c * 256 + wid * 64) * 8]); } while (0)

  // frag read: row = wm*128 + mf*16 + l15; phys chunk = (ks*4+quad)^(row&7),
  // row&7 == l15&7. Byte addr = row*128 + chunk*16.
  const int rx  = l15 & 7;
  const int co0 = (quad ^ rx) * 16;
  const int co1 = ((4 + quad) ^ rx) * 16;
  const int aro = (wm * 128 + l15) * 128;   // + mf*2048
  const int bro = (wn * 128 + l15) * 128;   // + nf*2048

#define LDA(BI, mf, CO) \
  (*(const short8*)((const char*)&As[BI][0] + aro + (mf) * 2048 + (CO)))
#define LDB(BI, nf, CO) \
  (*(const short8*)((const char*)&Bs[BI][0] + bro + (nf) * 2048 + (CO)))

  f32x4 acc[8][8];
  #pragma unroll
  for (int i = 0; i < 8; ++i)
    #pragma unroll
    for (int j = 0; j < 8; ++j)
      acc[i][j] = f32x4{0.f, 0.f, 0.f, 0.f};

  short8 fa0[8], fb0[8], fa1[8], fb1[8];

  // One K64-tile: all 32 frag reads issue first (both k-slices, two frag
  // sets), stage A(t+1) issues, then 64 MFMA (slice 0; compiler lgkm-waits
  // only on set0, set1 services underneath), stage B(t+1), 64 MFMA (slice
  // 1), vmcnt(0) (loads are 1240-2480cy old -> free), ONE barrier.
#define TILE(BI, APn, BPn, SK) do {                                            \
    _Pragma("unroll") for (int m = 0; m < 8; ++m) fa0[m] = LDA(BI, m, co0);    \
    _Pragma("unroll") for (int n = 0; n < 8; ++n) fb0[n] = LDB(BI, n, co0);    \
    _Pragma("unroll") for (int m = 0; m < 8; ++m) fa1[m] = LDA(BI, m, co1);    \
    _Pragma("unroll") for (int n = 0; n < 8; ++n) fb1[n] = LDB(BI, n, co1);    \
    if (!(SK)) STG_A((BI) ^ 1, APn);                                           \
    __builtin_amdgcn_s_setprio(1);                                             \
    _Pragma("unroll") for (int m = 0; m < 8; ++m)                              \
      _Pragma("unroll") for (int n = 0; n < 8; ++n)                            \
        acc[m][n] = __builtin_amdgcn_mfma_f32_16x16x32_bf16(                   \
            fa0[m], fb0[n], acc[m][n], 0, 0, 0);                               \
    __builtin_amdgcn_s_setprio(0);                                             \
    if (!(SK)) STG_B((BI) ^ 1, BPn);                                           \
    __builtin_amdgcn_s_setprio(1);                                             \
    _Pragma("unroll") for (int m = 0; m < 8; ++m)                              \
      _Pragma("unroll") for (int n = 0; n < 8; ++n)                            \
        acc[m][n] = __builtin_amdgcn_mfma_f32_16x16x32_bf16(                   \
            fa1[m], fb1[n], acc[m][n], 0, 0, 0);                               \
    __builtin_amdgcn_s_setprio(0);                                             \
    asm volatile("s_waitcnt vmcnt(0)" ::: "memory");                           \
    __builtin_amdgcn_s_barrier();                                              \
  } while (0)

  // ---- prologue: stage tile 0 of segment 0 into buf0 ----
  {
    const u16* A0 = X + (size_t)(u2 * BM) * D_IN;
    STG_A(0, A0);
    STG_B(0, Bu);
    asm volatile("s_waitcnt lgkmcnt(0)" ::: "memory");  // param ds_writes done
    asm volatile("s_waitcnt vmcnt(0)" ::: "memory");
    __builtin_amdgcn_s_barrier();
  }

  #pragma unroll 1
  for (int g = 0; g < NSEG; ++g) {
    const u16* AuC = X + (size_t)((g * 8 + u2) * BM) * D_IN;
    const u16* AuN = AuC + (size_t)(8 * BM) * D_IN;   // next segment (g<7)
    const bool lastseg = (g == NSEG - 1);

    #pragma unroll 1
    for (int j = 0; j < KTILES / 2; ++j) {
      // tile 2j (buf0) stages tile 2j+1 (always in-segment, 1..21)
      TILE(0, AuC + (2 * j + 1) * BK, Bu + (2 * j + 1) * BK, false);
      // tile 2j+1 (buf1) stages tile 2j+2 (wraps to next segment at j=10)
      const bool wrap = (j == KTILES / 2 - 1);
      const u16* Ap2 = wrap ? AuN : AuC + (2 * j + 2) * BK;
      const u16* Bp2 = Bu + (wrap ? 0 : (2 * j + 2)) * BK;
      TILE(1, Ap2, Bp2, lastseg && wrap);
    }

    // ---- fused epilogue (per segment): relu(acc+b1).W2, 2-wave combine ----
    // acc[mf][nf] elem (quad,r): row = wm*128+mf*16+quad*4+r,
    //                            col = wn*128+nf*16+l15
    {
      float b1v[8], w2v[8][3];
      #pragma unroll
      for (int n = 0; n < 8; ++n) {
        int col = wn * 128 + n * 16 + l15;
        b1v[n] = b1L[col];
        #pragma unroll
        for (int p = 0; p < 3; ++p) w2v[n][p] = w2L[col * 3 + p];
      }
      const int m0 = (g * 8 + u2) * BM;

      #pragma unroll
      for (int m = 0; m < 8; ++m) {
        float ps[4][3];
        #pragma unroll
        for (int r = 0; r < 4; ++r)
          #pragma unroll
          for (int p = 0; p < 3; ++p) ps[r][p] = 0.f;

        #pragma unroll
        for (int n = 0; n < 8; ++n)
          #pragma unroll
          for (int r = 0; r < 4; ++r) {
            float h = acc[m][n][r] + b1v[n];
            h = h > 0.f ? h : 0.f;
            #pragma unroll
            for (int p = 0; p < 3; ++p)
              ps[r][p] = fmaf(h, w2v[n][p], ps[r][p]);
          }

        // sum over the 16 column-lanes (xor on low 4 lane bits stays in-quad)
        #pragma unroll
        for (int mask = 1; mask < 16; mask <<= 1)
          #pragma unroll
          for (int r = 0; r < 4; ++r)
            #pragma unroll
            for (int p = 0; p < 3; ++p)
              ps[r][p] += __shfl_xor(ps[r][p], mask, 64);

        if (l15 == 0) {
          int row = wm * 128 + m * 16 + quad * 4;          // +r below
          #pragma unroll
          for (int r = 0; r < 4; ++r)
            #pragma unroll
            for (int p = 0; p < 3; ++p)
              scr[((row + r) * 3 + p) * 2 + wn] = ps[r][p];
        }
      }
      // raw barrier (NOT __syncthreads: next-seg tile0 DMA already landed at
      // the last tile's vmcnt(0); only ds ordering needed here)
      asm volatile("s_waitcnt lgkmcnt(0)" ::: "memory");
      __builtin_amdgcn_s_barrier();

      #pragma unroll
      for (int i = tid; i < BM * 3; i += 256) {
        int row = i / 3, p = i - row * 3;
        out[(size_t)(m0 + row) * (N_HEADS * 3) + head * 3 + p] =
            scr[i * 2] + scr[i * 2 + 1] + b2L[p];
      }

      #pragma unroll
      for (int i = 0; i < 8; ++i)
        #pragma unroll
        for (int jj = 0; jj < 8; ++jj)
          acc[i][jj] = f32x4{0.f, 0.f, 0.f, 0.f};
      // scr not rewritten until next epilogue, 22 tile-barriers away; next
      // TILE reads As/Bs (disjoint from scr) -> no extra barrier needed.
    }
  }

#undef STG_A
#undef STG_B
#undef LDA
#undef LDB
#undef TILE
}

extern "C" void kernel_launch(void* const* d_in, const int* in_sizes, int n_in,
                              void* d_out, int out_size, void* d_ws, size_t ws_size,
                              hipStream_t stream) {
  const float* X  = (const float*)d_in[0];
  const float* W1 = (const float*)d_in[1];
  const float* b1 = (const float*)d_in[2];
  const float* W2 = (const float*)d_in[3];
  const float* b2 = (const float*)d_in[4];

  // ws: Xb 46,137,344 | W1T 23,068,672  = 69,206,016 B (proven fits)
  u16* Xb  = (u16*)d_ws;
  u16* W1T = (u16*)((char*)d_ws + (size_t)BATCH * D_IN * 2);

  prep<<<CONV_BLOCKS + (D_IN / 64) * (D_HID / 64) * N_HEADS, 256, 0, stream>>>(
      (const float4*)X, (ushort4*)Xb, W1, W1T);

  mano_gemm<<<dim3(256), 256, 0, stream>>>(
      Xb, W1T, b1, W2, b2, (float*)d_out);
}

// Round 6
// 663.112 us; speedup vs baseline: 1.5415x; 1.5415x over previous
//
#include <hip/hip_runtime.h>
#include <hip/hip_bf16.h>
#include <stdint.h>

#define D_IN    1408
#define D_HID   256
#define N_HEADS 32
#define BATCH   16384

#define BM 256            // rows per block
#define BN 256            // full head of hidden units
#define BK 64
#define KTILES (D_IN / BK)   // 22, exact (even -> static double-buffer parity)
#define NSEG 8               // segments per persistent block

typedef unsigned short u16;
typedef short short8 __attribute__((ext_vector_type(8)));
typedef float f32x16 __attribute__((ext_vector_type(16)));

// All inputs and the output are float32 (reference dtypes); compute is bf16
// MFMA (absmax 7.8e-3 vs threshold 2.4e-2, verified R1-R5).
__device__ __forceinline__ u16 f2b(float f) {
  __hip_bfloat16 h = __float2bfloat16(f);
  return *(u16*)&h;
}

// async global->LDS DMA, 16B/lane; LDS dest = wave-uniform base + lane*16.
__device__ __forceinline__ void gload_lds16(const void* g, void* l) {
  __builtin_amdgcn_global_load_lds(
      (const __attribute__((address_space(1))) uint32_t*)((const uint32_t*)g),
      (__attribute__((address_space(3))) uint32_t*)((uint32_t*)l),
      16, 0, 0);
}

// ---------------------------------------------------------------------------
// Kernel 0 (fused prep): convert X f32->bf16  AND  transpose W1 -> W1T bf16.
// ---------------------------------------------------------------------------
#define CONV_BLOCKS 22528   // (BATCH*D_IN/4)/256 float4s
__global__ void prep(const float4* __restrict__ X, ushort4* __restrict__ Xb,
                     const float* __restrict__ W1, u16* __restrict__ W1T) {
  const int bid = blockIdx.x;
  const int tid = threadIdx.x;
  if (bid < CONV_BLOCKS) {
    int i = bid * 256 + tid;
    float4 v = X[i];
    ushort4 o;
    o.x = f2b(v.x); o.y = f2b(v.y); o.z = f2b(v.z); o.w = f2b(v.w);
    Xb[i] = o;
    return;
  }
  // transpose part: b = f + 22*(o + 4*h)
  __shared__ u16 tile[64][68];
  const int b  = bid - CONV_BLOCKS;
  const int f0 = (b % 22) * 64;
  const int o0 = ((b / 22) & 3) * 64;
  const int h  = b / 88;
  const int tx = tid & 63;
  const int ty = tid >> 6;          // 0..3
  const size_t ib = (size_t)h * D_IN * D_HID;
  #pragma unroll
  for (int i = ty; i < 64; i += 4)
    tile[i][tx] = f2b(W1[ib + (size_t)(f0 + i) * D_HID + o0 + tx]);
  __syncthreads();
  const size_t ob = (size_t)h * D_HID * D_IN;
  #pragma unroll
  for (int pass = 0; pass < 4; ++pass) {
    int r = pass * 16 + ty * 4 + (tx >> 4);  // 0..63
    int c = (tx & 15) * 4;                   // 0..60
    ushort4 v;
    v.x = tile[c + 0][r]; v.y = tile[c + 1][r];
    v.z = tile[c + 2][r]; v.w = tile[c + 3][r];
    *(ushort4*)&W1T[ob + (size_t)(o0 + r) * D_IN + f0 + c] = v;
  }
}

// ---------------------------------------------------------------------------
// Kernel 1: PERSISTENT 256x256 GEMM, 8 waves, mfma_32x32x16, k-slice pipe.
//
// R5 post-mortem: 1 wave/SIMD spills (compiler caps arch VGPR at 256);
// R3 calibration: at 2 waves/SIMD the compiler puts acc in AGPRs (120 arch
// + 128 acc = 248 = cap). The single-set frag WAR hazard that serialized
// LDS-reads against MFMA needs frag double-buffering; at 16x16x32 that is
// +64 VGPR (infeasible). At 32x32x16 a k16-slice's frags are only
// (4A+2B)x4 = 24 VGPR -> two sets = 48, fits. Also 32x32 peak = 2382 vs
// 2075 TF. Per K64-tile (4 slices, sets rotate, ONE barrier):
//   rd s0->set0; STG_A(t+1); rd s1->set1; STG_B(t+1);
//   MFMA s0; rd s2->set0; MFMA s1; rd s3->set1; MFMA s2; MFMA s3;
//   vmcnt(0); barrier
// Slice s+1's reads are serviced under slice s's MFMAs (counted lgkm waits;
// no WAR across sets). DMA lead = full tile (~2200cy) >> 900cy HBM latency
// -> the per-tile vmcnt(0) is free. Stage safety: STG targets buf^1, fully
// consumed last tile (ended with barrier).
// 32x32x16 operand map: lane=row/col (l&31), l>>5 picks 8-k half; LDS chunk
// = (2*ks + (l>>5)) ^ (row&7) on the same XOR-swizzled [row][k8] layout
// (16-lane subpasses -> 2 lanes/slot = conflict-free, as measured R1-R4).
// C/D: col=lane&31, row=(reg&3)+8*(reg>>2)+4*(lane>>5)  [m74/m101].
// Persistent head-constant blocks (b1/W2/b2 in LDS), 8 segments,
// cross-segment staging, epilogue untouched LDS As/Bs.
// ---------------------------------------------------------------------------
__global__ __launch_bounds__(512, 2) void mano_gemm(
    const u16* __restrict__ X,               // [16384][1408] bf16 (ws)
    const u16* __restrict__ W1T,             // [32][256][1408] bf16 (ws)
    const float* __restrict__ b1,            // [32][256] f32
    const float* __restrict__ W2,            // [32][256][3] f32
    const float* __restrict__ b2,            // [32][3] f32
    float* __restrict__ out)                 // [16384][96] f32 (d_out)
{
  __shared__ __align__(16) u16 As[2][BM * BK];   // 2 x 32 KB
  __shared__ __align__(16) u16 Bs[2][BN * BK];   // 2 x 32 KB
  __shared__ __align__(16) float scr[3072];      // 12 KB epilogue scratch
  __shared__ float b1L[256];                     // head-constant params
  __shared__ float w2L[768];
  __shared__ float b2L[3];

  const int tid  = threadIdx.x;     // 0..511
  const int lane = tid & 63;
  const int wid  = tid >> 6;        // 0..7
  const int l31  = lane & 31;
  const int lh   = lane >> 5;       // 0..1 (k-half)
  const int lx   = lane & 7;
  const int wm   = wid >> 2;        // 0..1 (128-row half)
  const int wn   = wid & 3;         // 0..3 (64-col band)

  const int bid  = blockIdx.x;              // 0..255
  const int head = (bid & 7) * 4 + ((bid >> 3) & 3);   // constant per block
  const int u2   = bid >> 5;                           // 0..7

  const u16* Bu = W1T + (size_t)head * D_HID * D_IN;

  // ---- head-constant params -> LDS (once) ----
  if (tid < 256) b1L[tid] = b1[head * D_HID + tid];
  for (int i = tid; i < 768; i += 512) w2L[i] = W2[(size_t)head * D_HID * 3 + i];
  if (tid < 3)  b2L[tid] = b2[head * 3 + tid];

  // staging: LDS chunk ci(16B) holds global [row=ci>>3][k8=(ci&7)^(row&7)]
  // (XOR pre-swizzled source, linear LDS). 2048 chunks / 512 threads = 4.
  int soff[4];
  #pragma unroll
  for (int c = 0; c < 4; ++c) {
    int ci  = c * 512 + tid;
    int row = ci >> 3;                 // 0..255
    int k8  = (ci & 7) ^ (row & 7);
    soff[c] = row * D_IN + k8 * 8;
  }

#define STG_A(BI, P) do { _Pragma("unroll")                                    \
    for (int c = 0; c < 4; ++c)                                                \
      gload_lds16((P) + soff[c], &As[BI][(c * 512 + wid * 64) * 8]); } while (0)
#define STG_B(BI, P) do { _Pragma("unroll")                                    \
    for (int c = 0; c < 4; ++c)                                                \
      gload_lds16((P) + soff[c], &Bs[BI][(c * 512 + wid * 64) * 8]); } while (0)

  // frag read: A row = wm*128 + mf*32 + l31, B row = wn*64 + nf*32 + l31;
  // chunk for slice s = (2s + lh) ^ (row&7), row&7 == lx. Row stride 128 B.
  const int cs0 = ((0 + lh) ^ lx) * 16;
  const int cs1 = ((2 + lh) ^ lx) * 16;
  const int cs2 = ((4 + lh) ^ lx) * 16;
  const int cs3 = ((6 + lh) ^ lx) * 16;
  const int aro = (wm * 128 + l31) * 128;   // + mf*4096
  const int bro = (wn * 64 + l31) * 128;    // + nf*4096

#define RD(BI, SET, CO) do {                                                   \
    _Pragma("unroll") for (int m = 0; m < 4; ++m)                              \
      fa[SET][m] = *(const short8*)((const char*)&As[BI][0] +                  \
                                    aro + m * 4096 + (CO));                    \
    _Pragma("unroll") for (int n = 0; n < 2; ++n)                              \
      fb[SET][n] = *(const short8*)((const char*)&Bs[BI][0] +                  \
                                    bro + n * 4096 + (CO)); } while (0)

#define MMB(SET) do {                                                          \
    __builtin_amdgcn_s_setprio(1);                                             \
    _Pragma("unroll") for (int m = 0; m < 4; ++m)                              \
      _Pragma("unroll") for (int n = 0; n < 2; ++n)                            \
        acc[m][n] = __builtin_amdgcn_mfma_f32_32x32x16_bf16(                   \
            fa[SET][m], fb[SET][n], acc[m][n], 0, 0, 0);                       \
    __builtin_amdgcn_s_setprio(0); } while (0)

  f32x16 acc[4][2];
  #pragma unroll
  for (int i = 0; i < 4; ++i)
    #pragma unroll
    for (int j = 0; j < 2; ++j)
      #pragma unroll
      for (int e = 0; e < 16; ++e)
        acc[i][j][e] = 0.f;

  short8 fa[2][4], fb[2][2];

  // One K64-tile, 4 k16-slices, 2 rotating frag sets, ONE barrier.
#define TILE(BI, APn, BPn, SK) do {                                            \
    RD(BI, 0, cs0);                                                            \
    if (!(SK)) STG_A((BI) ^ 1, APn);                                           \
    RD(BI, 1, cs1);                                                            \
    if (!(SK)) STG_B((BI) ^ 1, BPn);                                           \
    MMB(0);                                                                    \
    RD(BI, 0, cs2);                                                            \
    MMB(1);                                                                    \
    RD(BI, 1, cs3);                                                            \
    MMB(0);                                                                    \
    MMB(1);                                                                    \
    asm volatile("s_waitcnt vmcnt(0)" ::: "memory");                           \
    __builtin_amdgcn_s_barrier();                                              \
  } while (0)

  // ---- prologue: stage tile 0 of segment 0 into buf0 ----
  {
    const u16* A0 = X + (size_t)(u2 * BM) * D_IN;
    STG_A(0, A0);
    STG_B(0, Bu);
    asm volatile("s_waitcnt lgkmcnt(0)" ::: "memory");  // param ds_writes done
    asm volatile("s_waitcnt vmcnt(0)" ::: "memory");
    __builtin_amdgcn_s_barrier();
  }

  #pragma unroll 1
  for (int g = 0; g < NSEG; ++g) {
    const u16* AuC = X + (size_t)((g * 8 + u2) * BM) * D_IN;
    const u16* AuN = AuC + (size_t)(8 * BM) * D_IN;   // next segment (g<7)
    const bool lastseg = (g == NSEG - 1);

    #pragma unroll 1
    for (int j = 0; j < KTILES / 2; ++j) {
      // tile 2j (buf0) stages tile 2j+1 (always in-segment, 1..21)
      TILE(0, AuC + (2 * j + 1) * BK, Bu + (2 * j + 1) * BK, false);
      // tile 2j+1 (buf1) stages tile 2j+2 (wraps to next segment at j=10)
      const bool wrap = (j == KTILES / 2 - 1);
      const u16* Ap2 = wrap ? AuN : AuC + (2 * j + 2) * BK;
      const u16* Bp2 = Bu + (wrap ? 0 : (2 * j + 2)) * BK;
      TILE(1, Ap2, Bp2, lastseg && wrap);
    }

    // ---- fused epilogue (per segment): relu(acc+b1).W2, 4-wave combine ----
    // acc[mf][nf] elem e: row = wm*128+mf*32+(e&3)+8*(e>>2)+4*lh,
    //                     col = wn*64+nf*32+l31
    {
      float b1v[2], w2v[2][3];
      #pragma unroll
      for (int n = 0; n < 2; ++n) {
        int col = wn * 64 + n * 32 + l31;
        b1v[n] = b1L[col];
        #pragma unroll
        for (int p = 0; p < 3; ++p) w2v[n][p] = w2L[col * 3 + p];
      }
      const int m0 = (g * 8 + u2) * BM;

      #pragma unroll
      for (int m = 0; m < 4; ++m) {
        float ps[16][3];
        #pragma unroll
        for (int e = 0; e < 16; ++e)
          #pragma unroll
          for (int p = 0; p < 3; ++p) ps[e][p] = 0.f;

        #pragma unroll
        for (int n = 0; n < 2; ++n)
          #pragma unroll
          for (int e = 0; e < 16; ++e) {
            float h = acc[m][n][e] + b1v[n];
            h = h > 0.f ? h : 0.f;
            #pragma unroll
            for (int p = 0; p < 3; ++p)
              ps[e][p] = fmaf(h, w2v[n][p], ps[e][p]);
          }

        // sum over the 32 column-lanes (xor on low 5 lane bits keeps l>>5)
        #pragma unroll
        for (int mask = 1; mask < 32; mask <<= 1)
          #pragma unroll
          for (int e = 0; e < 16; ++e)
            #pragma unroll
            for (int p = 0; p < 3; ++p)
              ps[e][p] += __shfl_xor(ps[e][p], mask, 64);

        if (l31 == 0) {   // lanes 0 and 32 (different rows via lh)
          #pragma unroll
          for (int e = 0; e < 16; ++e) {
            int row = wm * 128 + m * 32 + (e & 3) + 8 * (e >> 2) + 4 * lh;
            #pragma unroll
            for (int p = 0; p < 3; ++p)
              scr[(row * 3 + p) * 4 + wn] = ps[e][p];
          }
        }
      }
      // raw barrier (NOT __syncthreads: no DMA in flight to drain; only ds)
      asm volatile("s_waitcnt lgkmcnt(0)" ::: "memory");
      __builtin_amdgcn_s_barrier();

      for (int i = tid; i < BM * 3; i += 512) {
        int row = i / 3, p = i - row * 3;
        out[(size_t)(m0 + row) * (N_HEADS * 3) + head * 3 + p] =
            scr[i * 4 + 0] + scr[i * 4 + 1] + scr[i * 4 + 2] + scr[i * 4 + 3]
            + b2L[p];
      }

      #pragma unroll
      for (int i = 0; i < 4; ++i)
        #pragma unroll
        for (int jj = 0; jj < 2; ++jj)
          #pragma unroll
          for (int e = 0; e < 16; ++e)
            acc[i][jj][e] = 0.f;
      // scr not rewritten until next epilogue, 22 tile-barriers away; next
      // TILE reads As/Bs (disjoint from scr) -> no extra barrier needed.
    }
  }

#undef STG_A
#undef STG_B
#undef RD
#undef MMB
#undef TILE
}

extern "C" void kernel_launch(void* const* d_in, const int* in_sizes, int n_in,
                              void* d_out, int out_size, void* d_ws, size_t ws_size,
                              hipStream_t stream) {
  const float* X  = (const float*)d_in[0];
  const float* W1 = (const float*)d_in[1];
  const float* b1 = (const float*)d_in[2];
  const float* W2 = (const float*)d_in[3];
  const float* b2 = (const float*)d_in[4];

  // ws: Xb 46,137,344 | W1T 23,068,672  = 69,206,016 B (proven fits)
  u16* Xb  = (u16*)d_ws;
  u16* W1T = (u16*)((char*)d_ws + (size_t)BATCH * D_IN * 2);

  prep<<<CONV_BLOCKS + (D_IN / 64) * (D_HID / 64) * N_HEADS, 256, 0, stream>>>(
      (const float4*)X, (ushort4*)Xb, W1, W1T);

  mano_gemm<<<dim3(256), 512, 0, stream>>>(
      Xb, W1T, b1, W2, b2, (float*)d_out);
}

// Round 7
// 589.986 us; speedup vs baseline: 1.7326x; 1.1239x over previous
//
#include <hip/hip_runtime.h>
#include <hip/hip_bf16.h>
#include <stdint.h>

#define D_IN    1408
#define D_HID   256
#define N_HEADS 32
#define BATCH   16384

#define BM 128            // rows per block
#define BN 256            // full head of hidden units (epilogue needs all 256)
#define BK 32
#define KTILES (D_IN / BK)   // 44, exact
#define NSEG 8               // segments per persistent block (16 blocks/head)
#define BUFU16 (BM * BK + BN * BK)   // 12288 u16 = 24 KB per buffer

typedef unsigned short u16;
typedef short short8 __attribute__((ext_vector_type(8)));
typedef float f32x4 __attribute__((ext_vector_type(4)));

// All inputs and the output are float32 (reference dtypes); compute is bf16
// MFMA (absmax 7.8e-3 vs threshold 2.4e-2, verified R1-R6).
__device__ __forceinline__ u16 f2b(float f) {
  __hip_bfloat16 h = __float2bfloat16(f);
  return *(u16*)&h;
}

// async global->LDS DMA, 16B/lane; LDS dest = wave-uniform base + lane*16.
__device__ __forceinline__ void gload_lds16(const void* g, void* l) {
  __builtin_amdgcn_global_load_lds(
      (const __attribute__((address_space(1))) uint32_t*)((const uint32_t*)g),
      (__attribute__((address_space(3))) uint32_t*)((uint32_t*)l),
      16, 0, 0);
}

// ---------------------------------------------------------------------------
// Kernel 0 (fused prep): convert X f32->bf16  AND  transpose W1 -> W1T bf16.
// ---------------------------------------------------------------------------
#define CONV_BLOCKS 22528   // (BATCH*D_IN/4)/256 float4s
__global__ void prep(const float4* __restrict__ X, ushort4* __restrict__ Xb,
                     const float* __restrict__ W1, u16* __restrict__ W1T) {
  const int bid = blockIdx.x;
  const int tid = threadIdx.x;
  if (bid < CONV_BLOCKS) {
    int i = bid * 256 + tid;
    float4 v = X[i];
    ushort4 o;
    o.x = f2b(v.x); o.y = f2b(v.y); o.z = f2b(v.z); o.w = f2b(v.w);
    Xb[i] = o;
    return;
  }
  // transpose part: b = f + 22*(o + 4*h)
  __shared__ u16 tile[64][68];
  const int b  = bid - CONV_BLOCKS;
  const int f0 = (b % 22) * 64;
  const int o0 = ((b / 22) & 3) * 64;
  const int h  = b / 88;
  const int tx = tid & 63;
  const int ty = tid >> 6;          // 0..3
  const size_t ib = (size_t)h * D_IN * D_HID;
  #pragma unroll
  for (int i = ty; i < 64; i += 4)
    tile[i][tx] = f2b(W1[ib + (size_t)(f0 + i) * D_HID + o0 + tx]);
  __syncthreads();
  const size_t ob = (size_t)h * D_HID * D_IN;
  #pragma unroll
  for (int pass = 0; pass < 4; ++pass) {
    int r = pass * 16 + ty * 4 + (tx >> 4);  // 0..63
    int c = (tx & 15) * 4;                   // 0..60
    ushort4 v;
    v.x = tile[c + 0][r]; v.y = tile[c + 1][r];
    v.z = tile[c + 2][r]; v.w = tile[c + 3][r];
    *(ushort4*)&W1T[ob + (size_t)(o0 + r) * D_IN + f0 + c] = v;
  }
}

// ---------------------------------------------------------------------------
// Kernel 1: PERSISTENT 128x256/BK32, 2 blocks/CU, 3-BUFFER counted-vmcnt.
//
// Ledger: R3 (256x256 serial) 398us = register-capped, no overlap possible.
// R4 (this shape, 2 buffers) 447us: only flaw = per-tile vmcnt(0) with a
// 1-tile (~300-600cy) staging lead << 900cy HBM latency -> BOTH co-resident
// blocks stalled on every tile. R6 (32x32 rotating sets) 525us: falsified
// (MfmaUtil fell, unexplained 34.6M bank conflicts) -> abandoned.
// This rev = R4 + the drain fix:
//   - THREE 24KB LDS buffers, stage tile t+2 during tile t -> 2-tile lead
//     (~1800-3000cy >> HBM latency). Tile end waits vmcnt(3): tile t+1's
//     3 loads (2 tiles old) must land; t+2's 3 stay in flight. Only the
//     global last 2 tiles drain to vmcnt(0).
//   - epilogue scratch OVERLAYS the free third buffer (the just-computed
//     one; in-flight DMA targets the other two) -> LDS/block = 3x24K + 4K
//     params = 76.5KB -> still 2 blocks/CU (the R4 TLP mechanism, m114:
//     independent blocks co-schedule MFMA and LDS pipes at max, not sum).
//   - everything else verbatim R4 (swizzle/offsets measured 0 conflicts;
//     VGPR 64 at launch_bounds(512,4) -> 16 waves/CU).
// ---------------------------------------------------------------------------
__global__ __launch_bounds__(512, 4) void mano_gemm(
    const u16* __restrict__ X,               // [16384][1408] bf16 (ws)
    const u16* __restrict__ W1T,             // [32][256][1408] bf16 (ws)
    const float* __restrict__ b1,            // [32][256] f32
    const float* __restrict__ W2,            // [32][256][3] f32
    const float* __restrict__ b2,            // [32][3] f32
    float* __restrict__ out)                 // [16384][96] f32 (d_out)
{
  __shared__ __align__(16) u16 tiles[3][BUFU16];   // 3 x 24 KB (A@0, B@4096)
  __shared__ float b1L[256];                       // head-constant params
  __shared__ float w2L[768];
  __shared__ float b2L[3];

  const int tid  = threadIdx.x;
  const int lane = tid & 63;
  const int wid  = tid >> 6;        // 0..7
  const int quad = lane >> 4;
  const int l15  = lane & 15;
  const int wm   = wid >> 2;        // 0..1 (64-row half)
  const int wn   = wid & 3;         // 0..3 (64-col band)

  const int bid  = blockIdx.x;              // 0..511
  const int head = (bid & 7) * 4 + ((bid >> 3) & 3);   // constant per block
  const int u    = bid >> 5;                           // 0..15

  const u16* Bu = W1T + (size_t)head * D_HID * D_IN;
  u16* lds = &tiles[0][0];

  // ---- head-constant params -> LDS (once) ----
  if (tid < 256) b1L[tid] = b1[head * D_HID + tid];
  for (int i = tid; i < 768; i += 512) w2L[i] = W2[(size_t)head * D_HID * 3 + i];
  if (tid < 3)  b2L[tid] = b2[head * 3 + tid];

  // staging offsets (u16 units). A: 512 chunks (1/thread); B: 1024 (2/thread).
  // LDS linear chunk ci holds global [row=ci>>2][c=(ci&3)^((row>>1)&3)]
  // (XOR pre-swizzled source, linear LDS dest; R4-verified, 0 conflicts).
  int aoff;
  {
    int row = tid >> 2, c = tid & 3;
    aoff = row * D_IN + (c ^ ((row >> 1) & 3)) * 8;
  }
  int boff[2];
  #pragma unroll
  for (int cc = 0; cc < 2; ++cc) {
    int ci = cc * 512 + tid;
    int row = ci >> 2, c = ci & 3;
    boff[cc] = row * D_IN + (c ^ ((row >> 1) & 3)) * 8;
  }

  // frag read: row r = w*64 + f*16 + l15; phys chunk = quad ^ ((r>>1)&3)
  // == quad ^ ((l15>>1)&3). Row stride 64 B; byte addr = r*64 + chunk*16.
  const int p16 = (quad ^ ((l15 >> 1) & 3)) * 16;
  const int abase = (wm * 64 + l15) * 64 + p16;     // + mf*1024
  const int bbase = (wn * 64 + l15) * 64 + p16;     // + nf*1024 (B @ +8192 B)

#define STG(BUFP, AP, BP) do {                                                 \
    gload_lds16((AP) + aoff, (BUFP) + wid * 512);                              \
    _Pragma("unroll")                                                          \
    for (int cc = 0; cc < 2; ++cc)                                             \
      gload_lds16((BP) + boff[cc],                                             \
                  (BUFP) + 4096 + cc * 4096 + wid * 512);                      \
  } while (0)

  f32x4 acc[4][4];
  #pragma unroll
  for (int i = 0; i < 4; ++i)
    #pragma unroll
    for (int j = 0; j < 4; ++j)
      acc[i][j] = f32x4{0.f, 0.f, 0.f, 0.f};

  short8 a[4], b[4];

  // ---- prologue: stage tiles 0,1 of segment 0 into bufs 0,1 ----
  {
    const u16* A0 = X + (size_t)(u * BM) * D_IN;
    STG(lds, A0, Bu);                               // tile 0 -> buf 0
    STG(lds + BUFU16, A0 + BK, Bu + BK);            // tile 1 -> buf 1
    asm volatile("s_waitcnt lgkmcnt(0)" ::: "memory");  // param ds_writes done
    asm volatile("s_waitcnt vmcnt(3)" ::: "memory");    // tile0 (oldest 3) landed
    __builtin_amdgcn_s_barrier();
  }

  int bq = 0;   // buffer index of the current tile (advances mod 3, no reset)

  #pragma unroll 1
  for (int g = 0; g < NSEG; ++g) {
    const u16* AuC = X + (size_t)((g * 16 + u) * BM) * D_IN;
    const u16* AuN = AuC + (size_t)(16 * BM) * D_IN;   // next segment (g<7)
    const bool lastseg = (g == NSEG - 1);

    #pragma unroll 1
    for (int kt = 0; kt < KTILES; ++kt) {
      // stage target = tile kt+2 (wraps into next segment's tiles 0,1)
      int k2 = kt + 2;
      const u16* Ab2 = AuC;
      bool skip = false;
      if (k2 >= KTILES) { k2 -= KTILES; Ab2 = AuN; skip = lastseg; }
      const bool drain = lastseg && (kt >= KTILES - 2);

      int bq2 = bq + 2; if (bq2 >= 3) bq2 -= 3;
      u16* bufC = lds + bq * BUFU16;
      u16* bufN = lds + bq2 * BUFU16;

      if (!skip) STG(bufN, Ab2 + k2 * BK, Bu + k2 * BK);

      #pragma unroll
      for (int mf = 0; mf < 4; ++mf)
        a[mf] = *(const short8*)((const char*)bufC + abase + mf * 1024);
      #pragma unroll
      for (int nf = 0; nf < 4; ++nf)
        b[nf] = *(const short8*)((const char*)bufC + 8192 + bbase + nf * 1024);

      __builtin_amdgcn_s_setprio(1);
      #pragma unroll
      for (int mf = 0; mf < 4; ++mf)
        #pragma unroll
        for (int nf = 0; nf < 4; ++nf)
          acc[mf][nf] = __builtin_amdgcn_mfma_f32_16x16x32_bf16(
              a[mf], b[nf], acc[mf][nf], 0, 0, 0);
      __builtin_amdgcn_s_setprio(0);

      // counted drain: tile kt+1 (issued 2 tiles ago) must be landed;
      // tile kt+2's 3 loads may stay in flight. Global tail: full drain.
      if (drain) { asm volatile("s_waitcnt vmcnt(0)" ::: "memory"); }
      else       { asm volatile("s_waitcnt vmcnt(3)" ::: "memory"); }
      __builtin_amdgcn_s_barrier();

      bq = bq + 1; if (bq >= 3) bq -= 3;
    }

    // ---- fused epilogue (per segment): relu(acc+b1).W2, 4-wave combine ----
    // scr OVERLAYS the free buffer: the just-computed tile's buffer
    // (bq+2 mod 3); in-flight DMA targets bufs bq and bq+1 (disjoint).
    // acc[mf][nf] elem (quad,r): row = wm*64+mf*16+quad*4+r (0..127),
    //                            col = wn*64+nf*16+l15
    {
      int bqf = bq + 2; if (bqf >= 3) bqf -= 3;
      float* scr = (float*)(lds + bqf * BUFU16);   // 1536 f32 = 6 KB <= 24 KB

      float b1v[4], w2v[4][3];
      #pragma unroll
      for (int nf = 0; nf < 4; ++nf) {
        int col = wn * 64 + nf * 16 + l15;
        b1v[nf] = b1L[col];
        #pragma unroll
        for (int p = 0; p < 3; ++p) w2v[nf][p] = w2L[col * 3 + p];
      }
      const int m0 = (g * 16 + u) * BM;

      #pragma unroll
      for (int mf = 0; mf < 4; ++mf) {
        float ps[4][3];
        #pragma unroll
        for (int r = 0; r < 4; ++r)
          #pragma unroll
          for (int p = 0; p < 3; ++p) ps[r][p] = 0.f;

        #pragma unroll
        for (int nf = 0; nf < 4; ++nf)
          #pragma unroll
          for (int r = 0; r < 4; ++r) {
            float h = acc[mf][nf][r] + b1v[nf];
            h = h > 0.f ? h : 0.f;
            #pragma unroll
            for (int p = 0; p < 3; ++p)
              ps[r][p] = fmaf(h, w2v[nf][p], ps[r][p]);
          }

        // sum over the 16 column-lanes (xor on low 4 lane bits stays in-quad)
        #pragma unroll
        for (int mask = 1; mask < 16; mask <<= 1)
          #pragma unroll
          for (int r = 0; r < 4; ++r)
            #pragma unroll
            for (int p = 0; p < 3; ++p)
              ps[r][p] += __shfl_xor(ps[r][p], mask, 64);

        if (l15 == 0) {
          int row = wm * 64 + mf * 16 + quad * 4;          // +r below
          #pragma unroll
          for (int r = 0; r < 4; ++r)
            #pragma unroll
            for (int p = 0; p < 3; ++p)
              scr[((row + r) * 3 + p) * 4 + wn] = ps[r][p];
        }
      }
      // raw barrier (NOT __syncthreads: next-seg DMA in flight, must not
      // drain vmcnt). lgkm(0): all scr ds_writes retired.
      asm volatile("s_waitcnt lgkmcnt(0)" ::: "memory");
      __builtin_amdgcn_s_barrier();

      for (int i = tid; i < BM * 3; i += 512) {
        int row = i / 3, p = i - row * 3;
        float v = scr[i * 4 + 0] + scr[i * 4 + 1] + scr[i * 4 + 2]
                + scr[i * 4 + 3] + b2L[p];
        out[(size_t)(m0 + row) * (N_HEADS * 3) + head * 3 + p] = v;
      }
      // ensure this wave's scr reads retired before any later DMA can be
      // issued into this buffer (next reuse is 2 tiles away; belt+braces).
      asm volatile("s_waitcnt lgkmcnt(0)" ::: "memory");

      #pragma unroll
      for (int i = 0; i < 4; ++i)
        #pragma unroll
        for (int jj = 0; jj < 4; ++jj)
          acc[i][jj] = f32x4{0.f, 0.f, 0.f, 0.f};
    }
  }

#undef STG
}

extern "C" void kernel_launch(void* const* d_in, const int* in_sizes, int n_in,
                              void* d_out, int out_size, void* d_ws, size_t ws_size,
                              hipStream_t stream) {
  const float* X  = (const float*)d_in[0];
  const float* W1 = (const float*)d_in[1];
  const float* b1 = (const float*)d_in[2];
  const float* W2 = (const float*)d_in[3];
  const float* b2 = (const float*)d_in[4];

  // ws: Xb 46,137,344 | W1T 23,068,672  = 69,206,016 B (proven fits)
  u16* Xb  = (u16*)d_ws;
  u16* W1T = (u16*)((char*)d_ws + (size_t)BATCH * D_IN * 2);

  prep<<<CONV_BLOCKS + (D_IN / 64) * (D_HID / 64) * N_HEADS, 256, 0, stream>>>(
      (const float4*)X, (ushort4*)Xb, W1, W1T);

  mano_gemm<<<dim3(512), 512, 0, stream>>>(
      Xb, W1T, b1, W2, b2, (float*)d_out);
}